// Round 4
// baseline (690.991 us; speedup 1.0000x reference)
//
#include <hip/hip_runtime.h>
#include <hip/hip_bf16.h>
#include <math.h>
#include <cstdint>

typedef unsigned long long u64;
typedef unsigned int u32;
typedef _Float16 half8 __attribute__((ext_vector_type(8)));
typedef float floatx4 __attribute__((ext_vector_type(4)));

// ---------------------------------------------------------------------------
// Sizes
// ---------------------------------------------------------------------------
#define NANCH 36864        // 4096*9
#define SEG 65536          // padded per-image sort segment
#define N_PRE 6000
#define N_POST 300
#define NW 96              // mask words per row (6144 bits)
#define NPADC 6144         // padded candidate count

// output float offsets
#define O0 0               // rpn_locs  2*36864*4 = 294912
#define O1 294912          // rpn_scores 2*36864*2 = 147456
#define O2 442368          // rois 2*300*4 = 2400
#define O3 444768          // roi_indices 600
#define O4 445368          // anchor 147456
#define O5 592824          // vmask 600

// workspace float offsets
#define WS_XHI   0                        // xhi f16 [2][4096][512] (2,097,152 f)
#define WS_XLO   2097152
#define WS_WHI   4194304                  // whi f16 [9][512][512] (1,179,648 f)
#define WS_WLO   5373952
#define WS_WSLT  6553600                  // 32768
#define WS_WSLB  6586368                  // 64
#define WS_H     6586432                  // hbuf f32 [2][4096][512] = 4,194,304 f
#define WS_GUARD 10780736                 // 64 floats of zeros (OOB target)
// overlays into dead XHI region (used only after conv completes):
#define WS_FG    0                        // 73728
#define WS_ROI   73728                    // 294912 (16B aligned)
#define WS_KEYS  368640                   // 131072 u64 = 262144 f
#define WS_SBOX  630784                   // 2*6144 float4 = 49152 f
#define WS_ALIVE 679936                   // 2*96 u64 = 384 f
// overlay into dead WHI+WLO region (after conv): suppression matrix
#define WS_MASK  4194304                  // 2*6144*96 u64 = 9,437,184 B (exact fit)

#define HSCALE 9.5367431640625e-07f       // 2^-20

// ---------------------------------------------------------------------------
__device__ __forceinline__ void gl_lds16(const void* g, void* l) {
  __builtin_amdgcn_global_load_lds(
      (const __attribute__((address_space(1))) u32*)g,
      (__attribute__((address_space(3))) u32*)l, 16, 0, 0);
}

__device__ __forceinline__ u64 bcast64(u64 v, int src) {
  u32 lo = (u32)__shfl((int)(v & 0xFFFFFFFFull), src);
  u32 hi = (u32)__shfl((int)(v >> 32), src);
  return ((u64)hi << 32) | lo;
}

// ---------------------------------------------------------------------------
// 0a. zero hbuf + guard page
// ---------------------------------------------------------------------------
__global__ __launch_bounds__(256) void zero_h(float4* __restrict__ h,
                                              float4* __restrict__ guard) {
  int idx = blockIdx.x * 256 + threadIdx.x;
  if (idx < 1048576) h[idx] = make_float4(0.f, 0.f, 0.f, 0.f);
  else if (idx < 1048576 + 16) guard[idx - 1048576] = make_float4(0.f, 0.f, 0.f, 0.f);
}

// ---------------------------------------------------------------------------
// 0b. x convert: [n][c][pix] f32 -> [n][pix][c] f16 hi/lo, scaled x1024.
// ---------------------------------------------------------------------------
__global__ __launch_bounds__(256) void xcvt(const float* __restrict__ x,
                                            _Float16* __restrict__ xhi,
                                            _Float16* __restrict__ xlo) {
  __shared__ float s[64 * 65];
  const int pt = blockIdx.x, cg = blockIdx.y, n = blockIdx.z;
  const int c0 = cg << 6, p0 = pt << 6;
  const int tid = threadIdx.x;
#pragma unroll
  for (int kk = 0; kk < 16; ++kk) {
    int e = tid + (kk << 8);
    int ci = e >> 6, pi = e & 63;
    s[ci * 65 + pi] = x[(((size_t)(n * 512 + c0 + ci)) << 12) + p0 + pi];
  }
  __syncthreads();
#pragma unroll
  for (int kk = 0; kk < 16; ++kk) {
    int e = tid + (kk << 8);
    int ci = e & 63, pi = e >> 6;
    float sv = s[ci * 65 + pi] * 1024.f;
    _Float16 hi = (_Float16)sv;
    _Float16 lo = (_Float16)(sv - (float)hi);
    size_t off = (((size_t)(n << 12) + p0 + pi) << 9) + c0 + ci;
    xhi[off] = hi;
    xlo[off] = lo;
  }
}

// ---------------------------------------------------------------------------
// 0c. conv weight convert: [o][c][3][3] f32 -> [t][o][c] f16 hi/lo, x1024.
// ---------------------------------------------------------------------------
__global__ __launch_bounds__(256) void wcvt(const float* __restrict__ w,
                                            _Float16* __restrict__ whi,
                                            _Float16* __restrict__ wlo) {
  const int ct = blockIdx.x, ot = blockIdx.y, t = blockIdx.z;
  const int c0 = ct << 6, o0 = ot << 6;
  const int tid = threadIdx.x;
#pragma unroll
  for (int kk = 0; kk < 16; ++kk) {
    int e = tid + (kk << 8);
    int ci = e & 63, oi = e >> 6;
    float sv = w[(size_t)(o0 + oi) * 4608 + (c0 + ci) * 9 + t] * 1024.f;
    _Float16 hi = (_Float16)sv;
    _Float16 lo = (_Float16)(sv - (float)hi);
    size_t off = ((size_t)((t << 9) + o0 + oi) << 9) + c0 + ci;
    whi[off] = hi;
    wlo[off] = lo;
  }
}

// ---------------------------------------------------------------------------
// 0d. pack 1x1 head weights + biases
// ---------------------------------------------------------------------------
__global__ __launch_bounds__(256) void prep_small(
    const float* __restrict__ lw, const float* __restrict__ sw,
    const float* __restrict__ lb, const float* __restrict__ sb,
    float* __restrict__ wslt, float* __restrict__ wslb) {
  int e = blockIdx.x * 256 + threadIdx.x;
  if (e < 32768) {
    int c = e >> 6, o = e & 63;
    float v = 0.f;
    if (o < 36) v = lw[o * 512 + c];
    else if (o < 54) v = sw[(o - 36) * 512 + c];
    wslt[e] = v;
  } else if (e < 32832) {
    int o = e - 32768;
    float v = 0.f;
    if (o < 36) v = lb[o];
    else if (o < 54) v = sb[o - 36];
    wslb[o] = v;
  }
}

// ---------------------------------------------------------------------------
// 1. MFMA implicit-GEMM 3x3 conv (fp16x2 split: hh + hl + lh, fp32 acc).
// ---------------------------------------------------------------------------
__global__ __launch_bounds__(256) void conv_mfma(
    const _Float16* __restrict__ xhi, const _Float16* __restrict__ xlo,
    const _Float16* __restrict__ whi, const _Float16* __restrict__ wlo,
    const float* __restrict__ guard, float* __restrict__ hout) {
  __shared__ _Float16 aHi[4 * 68 * 32];
  __shared__ _Float16 aLo[4 * 68 * 32];
  __shared__ _Float16 bHi[128 * 32];
  __shared__ _Float16 bLo[128 * 32];
  const int tid = threadIdx.x;
  const int lane = tid & 63, w = tid >> 6;
  const int ptile = blockIdx.x;
  const int og = blockIdx.y;
  const int kq = blockIdx.z;
  const int n = ptile >> 5;
  const int y0 = (ptile & 31) << 1;
  const int o0 = og << 7;
  const int l15 = lane & 15, l16 = lane >> 4;
  const int ry = w >> 1;
  const int wo = (w & 1) << 6;

  floatx4 acc[4][4];
#pragma unroll
  for (int a = 0; a < 4; ++a)
#pragma unroll
    for (int b = 0; b < 4; ++b) acc[a][b] = (floatx4)0.f;

  for (int s = 0; s < 8; ++s) {
    const int c0 = (kq << 8) + (s << 5);
    __syncthreads();
    for (int i = w; i < 17; i += 4) {
      int chunk = (i << 6) + lane;
      int p = chunk >> 2, q = chunk & 3;
      int r = p / 68, xs = p - r * 68;
      int y = y0 - 1 + r, xg = xs - 1;
      bool ok = ((unsigned)y < 64u) && ((unsigned)xg < 64u);
      size_t off = (((size_t)(n << 12) + (y << 6) + xg) << 9) + c0 + (q << 3);
      const void* gh = ok ? (const void*)(xhi + off) : (const void*)guard;
      const void* gl = ok ? (const void*)(xlo + off) : (const void*)guard;
      gl_lds16(gh, (char*)aHi + (i << 10));
      gl_lds16(gl, (char*)aLo + (i << 10));
    }
    for (int tt = 0; tt < 9; ++tt) {
      if (tt > 0) __syncthreads();
      for (int i = w; i < 8; i += 4) {
        int chunk = (i << 6) + lane;
        int row = chunk >> 2, q = chunk & 3;
        size_t off = ((size_t)((tt << 9) + o0 + row) << 9) + c0 + (q << 3);
        gl_lds16((const void*)(whi + off), (char*)bHi + (i << 10));
        gl_lds16((const void*)(wlo + off), (char*)bLo + (i << 10));
      }
      __syncthreads();

      const int dy = tt / 3, dx = tt - 3 * dy;
      half8 ah[4], al[4], bh[4], bl[4];
#pragma unroll
      for (int im = 0; im < 4; ++im) {
        int xp = (im << 4) + l15;
        int p = (ry + dy) * 68 + xp + dx;
        ah[im] = *(const half8*)&aHi[(p << 5) + (l16 << 3)];
        al[im] = *(const half8*)&aLo[(p << 5) + (l16 << 3)];
      }
#pragma unroll
      for (int in = 0; in < 4; ++in) {
        int orow = wo + (in << 4) + l15;
        bh[in] = *(const half8*)&bHi[(orow << 5) + (l16 << 3)];
        bl[in] = *(const half8*)&bLo[(orow << 5) + (l16 << 3)];
      }
#pragma unroll
      for (int im = 0; im < 4; ++im)
#pragma unroll
        for (int in = 0; in < 4; ++in) {
          acc[im][in] = __builtin_amdgcn_mfma_f32_16x16x32_f16(
              ah[im], bh[in], acc[im][in], 0, 0, 0);
          acc[im][in] = __builtin_amdgcn_mfma_f32_16x16x32_f16(
              ah[im], bl[in], acc[im][in], 0, 0, 0);
          acc[im][in] = __builtin_amdgcn_mfma_f32_16x16x32_f16(
              al[im], bh[in], acc[im][in], 0, 0, 0);
        }
    }
  }

#pragma unroll
  for (int im = 0; im < 4; ++im)
#pragma unroll
    for (int in = 0; in < 4; ++in) {
      int o = o0 + wo + (in << 4) + l15;
#pragma unroll
      for (int reg = 0; reg < 4; ++reg) {
        int m_local = (ry << 6) + (im << 4) + (l16 << 2) + reg;
        size_t off = (((size_t)(n << 12) + (y0 << 6) + m_local) << 9) + o;
        atomicAdd(&hout[off], acc[im][in][reg]);
      }
    }
}

// ---------------------------------------------------------------------------
// 2. 1x1 heads + softmax. grid (64 y, 2 n), block 256.
// ---------------------------------------------------------------------------
__global__ __launch_bounds__(256) void head_kernel(
    const float* __restrict__ hbuf, const float* __restrict__ cb,
    const float* __restrict__ wslt, const float* __restrict__ wslb,
    float* __restrict__ out, float* __restrict__ fgbuf) {
  const int y = blockIdx.x, n = blockIdx.y;
  __shared__ float sH[16 * 65];
  __shared__ float sWt[1024];
  __shared__ float sOut[64 * 65];
  const int tid = threadIdx.x;
  const int x = tid & 63, og = tid >> 6;

  float acc[16];
#pragma unroll
  for (int j = 0; j < 16; ++j) acc[j] = 0.f;

  const float* hb = hbuf + (((size_t)(n << 12) + (y << 6)) << 9);

  for (int c0 = 0; c0 < 512; c0 += 16) {
    __syncthreads();
#pragma unroll
    for (int p = 0; p < 4; ++p) {
      int e = tid + (p << 8);
      {
        int cc = e & 15, xx = e >> 4;
        float raw = hb[((size_t)xx << 9) + c0 + cc];
        sH[cc * 65 + xx] = fmaxf(raw * HSCALE + cb[c0 + cc], 0.f);
      }
      {
        int cc = e >> 6, xx = e & 63;
        sWt[e] = wslt[((c0 + cc) << 6) + xx];
      }
    }
    __syncthreads();
#pragma unroll
    for (int cc = 0; cc < 16; ++cc) {
      float hv = sH[cc * 65 + x];
      const float4* wp = (const float4*)&sWt[(cc << 6) + (og << 4)];
      float4 w0 = wp[0], w1 = wp[1], w2 = wp[2], w3 = wp[3];
      acc[0]  = fmaf(hv, w0.x, acc[0]);  acc[1]  = fmaf(hv, w0.y, acc[1]);
      acc[2]  = fmaf(hv, w0.z, acc[2]);  acc[3]  = fmaf(hv, w0.w, acc[3]);
      acc[4]  = fmaf(hv, w1.x, acc[4]);  acc[5]  = fmaf(hv, w1.y, acc[5]);
      acc[6]  = fmaf(hv, w1.z, acc[6]);  acc[7]  = fmaf(hv, w1.w, acc[7]);
      acc[8]  = fmaf(hv, w2.x, acc[8]);  acc[9]  = fmaf(hv, w2.y, acc[9]);
      acc[10] = fmaf(hv, w2.z, acc[10]); acc[11] = fmaf(hv, w2.w, acc[11]);
      acc[12] = fmaf(hv, w3.x, acc[12]); acc[13] = fmaf(hv, w3.y, acc[13]);
      acc[14] = fmaf(hv, w3.z, acc[14]); acc[15] = fmaf(hv, w3.w, acc[15]);
    }
  }
  __syncthreads();
#pragma unroll
  for (int j = 0; j < 16; ++j) {
    int o = (og << 4) + j;
    sOut[o * 65 + x] = acc[j] + wslb[o];
  }
  __syncthreads();

  const int p0 = (n << 12) + (y << 6);
  float* locs = out + O0 + (size_t)p0 * 36;
  for (int e = tid; e < 2304; e += 256) {
    int xx = e / 36, o = e - xx * 36;
    locs[e] = sOut[o * 65 + xx];
  }
  float* scrs = out + O1 + (size_t)p0 * 18;
  for (int e = tid; e < 1152; e += 256) {
    int xx = e / 18, ss = e - xx * 18;
    scrs[e] = sOut[(36 + ss) * 65 + xx];
  }
  float* fg = fgbuf + n * NANCH + (y << 6) * 9;
  for (int e = tid; e < 576; e += 256) {
    int xx = e / 9, a = e - xx * 9;
    float s0 = sOut[(36 + 2 * a) * 65 + xx];
    float s1 = sOut[(36 + 2 * a + 1) * 65 + xx];
    fg[e] = 1.0f / (1.0f + expf(s0 - s1));
  }
}

// ---------------------------------------------------------------------------
// 3. anchors + decode + clip + min-size + sort keys (+ init out regions).
// ---------------------------------------------------------------------------
__global__ __launch_bounds__(256) void decode_kernel(
    const float* __restrict__ out0, const float* __restrict__ fgbuf,
    float4* __restrict__ roibuf, u64* __restrict__ keys,
    float* __restrict__ anchor_out, float* __restrict__ out,
    const int* __restrict__ imgh_p, const int* __restrict__ imgw_p) {
  int gid = blockIdx.x * 256 + threadIdx.x;   // < 131072
  // folded init of rois / roi_indices / vmask
  if (gid < 3600) {
    if (gid < 2400) out[O2 + gid] = 0.f;
    else if (gid < 3000) out[O3 + (gid - 2400)] = (float)((gid - 2400) / 300);
    else out[O5 + (gid - 3000)] = 0.f;
  }
  int n = gid >> 16, k = gid & (SEG - 1);
  if (k >= NANCH) { keys[gid] = ~0ull; return; }
  int a = k % 9;
  int p = k / 9;
  int py = p >> 6, px = p & 63;

  const double R[3] = {0.5, 1.0, 2.0};
  const double S[3] = {8.0, 16.0, 32.0};
  double r = R[a / 3], s = S[a - (a / 3) * 3];
  double hd = 16.0 * s * sqrt(r);
  double wd = 16.0 * s * sqrt(1.0 / r);
  float ay1 = (float)(8.0 - hd / 2.0) + (float)(py * 16);
  float ax1 = (float)(8.0 - wd / 2.0) + (float)(px * 16);
  float ay2 = (float)(8.0 + hd / 2.0) + (float)(py * 16);
  float ax2 = (float)(8.0 + wd / 2.0) + (float)(px * 16);
  if (n == 0) {
    float* ao = anchor_out + (size_t)k * 4;
    ao[0] = ay1; ao[1] = ax1; ao[2] = ay2; ao[3] = ax2;
  }
  float ahk = ay2 - ay1, awk = ax2 - ax1;
  float acy = ay1 + 0.5f * ahk, acx = ax1 + 0.5f * awk;
  const float* lp = out0 + ((size_t)(n * NANCH + k) << 2);
  float dy = lp[0], dx = lp[1], dh = lp[2], dw = lp[3];
  float cy = dy * ahk + acy;
  float cx = dx * awk + acx;
  float bh = expf(dh) * ahk;
  float bw = expf(dw) * awk;
  float img_h = (float)imgh_p[0], img_w = (float)imgw_p[0];
  float y1 = fminf(fmaxf(cy - 0.5f * bh, 0.f), img_h);
  float x1 = fminf(fmaxf(cx - 0.5f * bw, 0.f), img_w);
  float y2 = fminf(fmaxf(cy + 0.5f * bh, 0.f), img_h);
  float x2 = fminf(fmaxf(cx + 0.5f * bw, 0.f), img_w);
  bool valid = ((y2 - y1) >= 16.f) && ((x2 - x1) >= 16.f);
  float sc = valid ? fgbuf[n * NANCH + k] : -INFINITY;
  roibuf[n * NANCH + k] = make_float4(y1, x1, y2, x2);
  unsigned int b = __float_as_uint(sc);
  unsigned int m = b ^ ((b & 0x80000000u) ? 0xFFFFFFFFu : 0x80000000u);
  keys[gid] = ((u64)(~m) << 32) | (unsigned int)k;
}

// ---------------------------------------------------------------------------
// 5. bitonic sort (u64 keys, ascending per 65536 segment), 11 launches
// ---------------------------------------------------------------------------
__global__ __launch_bounds__(256) void sort_local_a(u64* __restrict__ keys) {
  __shared__ u64 sk[4096];
  const int base = blockIdx.x << 12;
  for (int e = threadIdx.x; e < 4096; e += 256) sk[e] = keys[base + e];
  __syncthreads();
  for (int k = 2; k <= 4096; k <<= 1) {
    for (int j = k >> 1; j > 0; j >>= 1) {
      for (int t = threadIdx.x; t < 2048; t += 256) {
        int l = ((t & ~(j - 1)) << 1) | (t & (j - 1));
        int rr = l | j;
        bool asc = (((base + l) & k) == 0);
        u64 a = sk[l], b = sk[rr];
        if ((a > b) == asc) { sk[l] = b; sk[rr] = a; }
      }
      __syncthreads();
    }
  }
  for (int e = threadIdx.x; e < 4096; e += 256) keys[base + e] = sk[e];
}

__global__ __launch_bounds__(256) void sort_global_pass(u64* __restrict__ keys,
                                                        int k, int j) {
  int t = blockIdx.x * 256 + threadIdx.x;
  int l = ((t & ~(j - 1)) << 1) | (t & (j - 1));
  int rr = l | j;
  bool asc = (((l & (SEG - 1)) & k) == 0);
  u64 a = keys[l], b = keys[rr];
  if ((a > b) == asc) { keys[l] = b; keys[rr] = a; }
}

__global__ __launch_bounds__(256) void sort_global_pass2(u64* __restrict__ keys,
                                                         int k, int j1) {
  int t = blockIdx.x * 256 + threadIdx.x;
  int j2 = j1 >> 1;
  int l = ((t & ~(j2 - 1)) << 1) | (t & (j2 - 1));
  l = ((l & ~(j1 - 1)) << 1) | (l & (j1 - 1));
  u64 e0 = keys[l], e1 = keys[l | j2], e2 = keys[l | j1], e3 = keys[l | j1 | j2];
  bool asc = (((l & (SEG - 1)) & k) == 0);
  u64 tmp;
  if ((e0 > e2) == asc) { tmp = e0; e0 = e2; e2 = tmp; }
  if ((e1 > e3) == asc) { tmp = e1; e1 = e3; e3 = tmp; }
  if ((e0 > e1) == asc) { tmp = e0; e0 = e1; e1 = tmp; }
  if ((e2 > e3) == asc) { tmp = e2; e2 = e3; e3 = tmp; }
  keys[l] = e0; keys[l | j2] = e1; keys[l | j1] = e2; keys[l | j1 | j2] = e3;
}

__global__ __launch_bounds__(256) void sort_local_b(u64* __restrict__ keys, int k) {
  __shared__ u64 sk[4096];
  const int base = blockIdx.x << 12;
  for (int e = threadIdx.x; e < 4096; e += 256) sk[e] = keys[base + e];
  __syncthreads();
  for (int j = 2048; j > 0; j >>= 1) {
    for (int t = threadIdx.x; t < 2048; t += 256) {
      int l = ((t & ~(j - 1)) << 1) | (t & (j - 1));
      int rr = l | j;
      bool asc = ((((base + l) & (SEG - 1)) & k) == 0);
      u64 a = sk[l], b = sk[rr];
      if ((a > b) == asc) { sk[l] = b; sk[rr] = a; }
    }
    __syncthreads();
  }
  for (int e = threadIdx.x; e < 4096; e += 256) keys[base + e] = sk[e];
}

// ---------------------------------------------------------------------------
// 6a. gather sorted boxes + alive bitmask words. grid (24, 2), block 256.
// ---------------------------------------------------------------------------
__global__ __launch_bounds__(256) void nms_gather(
    const u64* __restrict__ keys, const float4* __restrict__ roibuf,
    float4* __restrict__ sbox, u64* __restrict__ alive) {
  const int n = blockIdx.y;
  int i = blockIdx.x * 256 + threadIdx.x;  // 0..6143
  u64 kk = (i < N_PRE) ? keys[(n << 16) + i] : ~0ull;
  bool valid = ((unsigned)(kk >> 32)) < 0xFF800000u;
  float4 b = make_float4(0.f, 0.f, 0.f, 0.f);
  if (valid) b = roibuf[(size_t)n * NANCH + (unsigned)(kk & 0xFFFFFFFFull)];
  sbox[n * NPADC + i] = b;
  u64 bal = __ballot(valid);
  if ((threadIdx.x & 63) == 0) alive[n * NW + (i >> 6)] = bal;
}

// ---------------------------------------------------------------------------
// 6b. build suppression matrix, upper word-triangle (w >= i>>6).
// M[n][i][w] bit b = IoU(box i, box 64w+b) > 0.7.  grid (96, 2), block 256.
// ---------------------------------------------------------------------------
__global__ __launch_bounds__(256) void build_mask(
    const float4* __restrict__ sbox, u64* __restrict__ M) {
  __shared__ float4 jb[4][64];
  __shared__ float ja[4][64];
  const int tid = threadIdx.x, lane = tid & 63, wv = tid >> 6;
  const int g = blockIdx.x, n = blockIdx.y;
  const float4* sb = sbox + n * NPADC;
  float4 bi = sb[(g << 6) + lane];
  float ai = (bi.z - bi.x) * (bi.w - bi.y);
  u64* Mrow = M + ((size_t)(n * NPADC + (g << 6) + lane)) * NW;
  const int itN = ((NW - g) + 3) >> 2;
  for (int it = 0; it < itN; ++it) {
    int w = g + wv + (it << 2);
    if (w < NW) {
      float4 bj = sb[(w << 6) + lane];
      jb[wv][lane] = bj;
      ja[wv][lane] = (bj.z - bj.x) * (bj.w - bj.y);
    }
    __syncthreads();
    if (w < NW) {
      u64 bits = 0;
#pragma unroll 8
      for (int j = 0; j < 64; ++j) {
        float4 bj = jb[wv][j];
        float aj = ja[wv][j];
        float ih = fmaxf(fminf(bi.z, bj.z) - fmaxf(bi.x, bj.x), 0.f);
        float iw = fmaxf(fminf(bi.w, bj.w) - fmaxf(bi.y, bj.y), 0.f);
        float inter = ih * iw;
        bool bit = inter / (ai + aj - inter + 1e-9f) > 0.7f;
        bits |= ((u64)bit) << j;
      }
      Mrow[w] = bits;
    }
    __syncthreads();
  }
}

// ---------------------------------------------------------------------------
// 6c. serial greedy reduce, one wave per image. All state in registers:
// lane L holds suppressed-acc words L and 64+L. Per chunk, resolve cost is
// O(kept-in-chunk) via ctz + ballot column elimination.
// ---------------------------------------------------------------------------
__global__ __launch_bounds__(64) void nms_reduce(
    const u64* __restrict__ M, const u64* __restrict__ alive,
    const float4* __restrict__ sbox, float* __restrict__ out) {
  const int n = blockIdx.x, lane = threadIdx.x;
  float* rois = out + O2 + n * (N_POST * 4);
  float* vmask = out + O5 + n * N_POST;
  const u64* A = alive + n * NW;
  const u64* Mb = M + (size_t)n * NPADC * NW;
  u64 aw0 = A[lane];
  u64 aw1 = (lane < NW - 64) ? A[64 + lane] : 0ull;
  u64 accA = 0, accB = 0;
  int nk = 0;
  u64 dnext = Mb[(size_t)lane * NW + 0];
  const u64 below = lane ? (~0ull >> (64 - lane)) : 0ull;

  for (int c = 0; c < 94; ++c) {
    u64 dcur = dnext;
    if (c + 1 < 94) dnext = Mb[(size_t)(((c + 1) << 6) + lane) * NW + (c + 1)];
    u64 wacc = (c < 64) ? bcast64(accA, c) : bcast64(accB, c - 64);
    u64 aw = (c < 64) ? bcast64(aw0, c) : bcast64(aw1, c - 64);
    u64 alive_u = aw & ~wacc;
    if (alive_u == 0ull) continue;

    u64 dmask = dcur & below;  // suppressors j < lane within chunk
    u64 rem = alive_u, kept = 0;
    while (rem) {
      int j = __builtin_ctzll(rem);          // uniform across wave
      kept |= 1ull << j;
      u64 col = __ballot((dmask >> j) & 1);  // who j suppresses (i > j)
      rem &= ~(col | (1ull << j));
    }

    int npop = __popcll(kept);
    if ((kept >> lane) & 1ull) {
      int slot = nk + __popcll(kept & below);
      if (slot < N_POST) {
        float4 b = sbox[n * NPADC + (c << 6) + lane];
        rois[slot * 4 + 0] = b.x; rois[slot * 4 + 1] = b.y;
        rois[slot * 4 + 2] = b.z; rois[slot * 4 + 3] = b.w;
        vmask[slot] = 1.0f;
      }
    }
    if (nk + npop >= N_POST) break;
    nk += npop;

    // OR kept rows (words >= c only; lower triangle is uninitialized)
    u64 kk = kept;
    while (kk) {
      int j = __builtin_ctzll(kk);
      kk &= kk - 1;
      const u64* row = Mb + (size_t)((c << 6) + j) * NW;
      if (lane >= c) accA |= row[lane];
      if (lane < NW - 64 && (64 + lane) >= c) accB |= row[64 + lane];
    }
  }
}

// ---------------------------------------------------------------------------
extern "C" void kernel_launch(void* const* d_in, const int* in_sizes, int n_in,
                              void* d_out, int out_size, void* d_ws, size_t ws_size,
                              hipStream_t stream) {
  const float* x        = (const float*)d_in[0];
  const float* conv1_w  = (const float*)d_in[1];
  const float* conv1_b  = (const float*)d_in[2];
  const float* score_w  = (const float*)d_in[3];
  const float* score_b  = (const float*)d_in[4];
  const float* loc_w    = (const float*)d_in[5];
  const float* loc_b    = (const float*)d_in[6];
  const int*   imgh_p   = (const int*)d_in[7];
  const int*   imgw_p   = (const int*)d_in[8];

  float* out = (float*)d_out;
  float* ws  = (float*)d_ws;

  _Float16* xhi = (_Float16*)(ws + WS_XHI);
  _Float16* xlo = (_Float16*)(ws + WS_XLO);
  _Float16* whi = (_Float16*)(ws + WS_WHI);
  _Float16* wlo = (_Float16*)(ws + WS_WLO);
  float* wslt   = ws + WS_WSLT;
  float* wslb   = ws + WS_WSLB;
  float* hbuf   = ws + WS_H;
  float* guard  = ws + WS_GUARD;
  // overlays (xhi region is dead after conv)
  float* fgbuf   = ws + WS_FG;
  float4* roibuf = (float4*)(ws + WS_ROI);
  u64* keys      = (u64*)(ws + WS_KEYS);
  float4* sbox   = (float4*)(ws + WS_SBOX);
  u64* alive     = (u64*)(ws + WS_ALIVE);
  u64* maskbuf   = (u64*)(ws + WS_MASK);   // overlays whi/wlo (dead after conv)

  zero_h<<<4097, 256, 0, stream>>>((float4*)hbuf, (float4*)guard);
  xcvt<<<dim3(64, 8, 2), 256, 0, stream>>>(x, xhi, xlo);
  wcvt<<<dim3(8, 8, 9), 256, 0, stream>>>(conv1_w, whi, wlo);
  prep_small<<<129, 256, 0, stream>>>(loc_w, score_w, loc_b, score_b, wslt, wslb);

  conv_mfma<<<dim3(64, 4, 2), 256, 0, stream>>>(xhi, xlo, whi, wlo, guard, hbuf);

  head_kernel<<<dim3(64, 2), 256, 0, stream>>>(hbuf, conv1_b, wslt, wslb, out, fgbuf);
  decode_kernel<<<512, 256, 0, stream>>>(out, fgbuf, roibuf, keys,
                                         out + O4, out, imgh_p, imgw_p);

  sort_local_a<<<32, 256, 0, stream>>>(keys);
  for (int k = 8192; k <= SEG; k <<= 1) {
    int j = k >> 1;
    while (j >= 4096) {
      if (j >= 8192) {
        sort_global_pass2<<<128, 256, 0, stream>>>(keys, k, j);
        j >>= 2;
      } else {
        sort_global_pass<<<256, 256, 0, stream>>>(keys, k, j);
        j >>= 1;
      }
    }
    sort_local_b<<<32, 256, 0, stream>>>(keys, k);
  }

  nms_gather<<<dim3(24, 2), 256, 0, stream>>>(keys, roibuf, sbox, alive);
  build_mask<<<dim3(96, 2), 256, 0, stream>>>(sbox, maskbuf);
  nms_reduce<<<2, 64, 0, stream>>>(maskbuf, alive, sbox, out);
}

// Round 5
// 499.165 us; speedup vs baseline: 1.3843x; 1.3843x over previous
//
#include <hip/hip_runtime.h>
#include <hip/hip_bf16.h>
#include <math.h>
#include <cstdint>

typedef unsigned long long u64;
typedef unsigned int u32;
typedef _Float16 half8 __attribute__((ext_vector_type(8)));
typedef float floatx4 __attribute__((ext_vector_type(4)));

// ---------------------------------------------------------------------------
// Sizes
// ---------------------------------------------------------------------------
#define NANCH 36864        // 4096*9
#define SEG 65536          // padded per-image sort segment
#define N_PRE 6000
#define N_POST 300
#define NW 96              // mask words per row (6144 bits)
#define NPADC 6144         // padded candidate count

// output float offsets
#define O0 0               // rpn_locs  2*36864*4 = 294912
#define O1 294912          // rpn_scores 2*36864*2 = 147456
#define O2 442368          // rois 2*300*4 = 2400
#define O3 444768          // roi_indices 600
#define O4 445368          // anchor 147456
#define O5 592824          // vmask 600

// workspace float offsets
#define WS_XHI   0                        // xhi f16 [2][4096][512] (2,097,152 f)
#define WS_XLO   2097152
#define WS_WHI   4194304                  // whi f16 [9][512][512] (1,179,648 f)
#define WS_WLO   5373952
#define WS_WSLT  6553600                  // 32768
#define WS_WSLB  6586368                  // 64
#define WS_H     6586432                  // hbuf f32 [2][4096][512] = 4,194,304 f
#define WS_GUARD 10780736                 // 64 floats of zeros (OOB target)
// overlays into dead XHI region (used only after conv completes):
#define WS_FG    0                        // 73728
#define WS_ROI   73728                    // 294912 (16B aligned)
#define WS_KEYS  368640                   // 131072 u64 = 262144 f
#define WS_SBOX  630784                   // 2*6144 float4 = 49152 f
#define WS_ALIVE 679936                   // 2*96 u64 = 384 f
// overlay into dead WHI+WLO region (after conv): FULL suppression matrix
#define WS_MASK  4194304                  // 2*6144*96 u64 = 9,437,184 B (exact fit)

#define HSCALE 9.5367431640625e-07f       // 2^-20

// ---------------------------------------------------------------------------
__device__ __forceinline__ void gl_lds16(const void* g, void* l) {
  __builtin_amdgcn_global_load_lds(
      (const __attribute__((address_space(1))) u32*)g,
      (__attribute__((address_space(3))) u32*)l, 16, 0, 0);
}

__device__ __forceinline__ u64 bcast64(u64 v, int src) {
  u32 lo = (u32)__shfl((int)(v & 0xFFFFFFFFull), src);
  u32 hi = (u32)__shfl((int)(v >> 32), src);
  return ((u64)hi << 32) | lo;
}

// ---------------------------------------------------------------------------
// 0. fused prep: zero hbuf+guard | xcvt | wcvt | head-weight pack.
// Linear grid: [0,4097) zero, [4097,5121) xcvt, [5121,5697) wcvt,
// [5697,5826) prep_small.
// ---------------------------------------------------------------------------
__global__ __launch_bounds__(256) void prep_all(
    const float* __restrict__ x, const float* __restrict__ w,
    const float* __restrict__ lw, const float* __restrict__ sw,
    const float* __restrict__ lb, const float* __restrict__ sb,
    float4* __restrict__ h, float4* __restrict__ guard,
    _Float16* __restrict__ xhi, _Float16* __restrict__ xlo,
    _Float16* __restrict__ whi, _Float16* __restrict__ wlo,
    float* __restrict__ wslt, float* __restrict__ wslb) {
  __shared__ float s[64 * 65];
  const int b = blockIdx.x, tid = threadIdx.x;
  if (b < 4097) {
    int idx = b * 256 + tid;
    if (idx < 1048576) h[idx] = make_float4(0.f, 0.f, 0.f, 0.f);
    else if (idx < 1048576 + 16) guard[idx - 1048576] = make_float4(0.f, 0.f, 0.f, 0.f);
    return;
  }
  if (b < 5121) {  // xcvt: [n][c][pix] f32 -> [n][pix][c] f16 hi/lo x1024
    int l = b - 4097;
    int pt = l & 63, cg = (l >> 6) & 7, n = l >> 9;
    const int c0 = cg << 6, p0 = pt << 6;
#pragma unroll
    for (int kk = 0; kk < 16; ++kk) {
      int e = tid + (kk << 8);
      int ci = e >> 6, pi = e & 63;
      s[ci * 65 + pi] = x[(((size_t)(n * 512 + c0 + ci)) << 12) + p0 + pi];
    }
    __syncthreads();
#pragma unroll
    for (int kk = 0; kk < 16; ++kk) {
      int e = tid + (kk << 8);
      int ci = e & 63, pi = e >> 6;
      float sv = s[ci * 65 + pi] * 1024.f;
      _Float16 hi = (_Float16)sv;
      _Float16 lo = (_Float16)(sv - (float)hi);
      size_t off = (((size_t)(n << 12) + p0 + pi) << 9) + c0 + ci;
      xhi[off] = hi;
      xlo[off] = lo;
    }
    return;
  }
  if (b < 5697) {  // wcvt: [o][c][3][3] -> [t][o][c] f16 hi/lo x1024
    int l = b - 5121;
    int ct = l & 7, ot = (l >> 3) & 7, t = l >> 6;
    const int c0 = ct << 6, o0 = ot << 6;
#pragma unroll
    for (int kk = 0; kk < 16; ++kk) {
      int e = tid + (kk << 8);
      int ci = e & 63, oi = e >> 6;
      float sv = w[(size_t)(o0 + oi) * 4608 + (c0 + ci) * 9 + t] * 1024.f;
      _Float16 hi = (_Float16)sv;
      _Float16 lo = (_Float16)(sv - (float)hi);
      size_t off = ((size_t)((t << 9) + o0 + oi) << 9) + c0 + ci;
      whi[off] = hi;
      wlo[off] = lo;
    }
    return;
  }
  {  // prep_small
    int e = (b - 5697) * 256 + tid;
    if (e < 32768) {
      int c = e >> 6, o = e & 63;
      float v = 0.f;
      if (o < 36) v = lw[o * 512 + c];
      else if (o < 54) v = sw[(o - 36) * 512 + c];
      wslt[e] = v;
    } else if (e < 32832) {
      int o = e - 32768;
      float v = 0.f;
      if (o < 36) v = lb[o];
      else if (o < 54) v = sb[o - 36];
      wslb[o] = v;
    }
  }
}

// ---------------------------------------------------------------------------
// 1. MFMA implicit-GEMM 3x3 conv (fp16x2 split: hh + hl + lh, fp32 acc).
// ---------------------------------------------------------------------------
__global__ __launch_bounds__(256) void conv_mfma(
    const _Float16* __restrict__ xhi, const _Float16* __restrict__ xlo,
    const _Float16* __restrict__ whi, const _Float16* __restrict__ wlo,
    const float* __restrict__ guard, float* __restrict__ hout) {
  __shared__ _Float16 aHi[4 * 68 * 32];
  __shared__ _Float16 aLo[4 * 68 * 32];
  __shared__ _Float16 bHi[128 * 32];
  __shared__ _Float16 bLo[128 * 32];
  const int tid = threadIdx.x;
  const int lane = tid & 63, w = tid >> 6;
  const int ptile = blockIdx.x;
  const int og = blockIdx.y;
  const int kq = blockIdx.z;
  const int n = ptile >> 5;
  const int y0 = (ptile & 31) << 1;
  const int o0 = og << 7;
  const int l15 = lane & 15, l16 = lane >> 4;
  const int ry = w >> 1;
  const int wo = (w & 1) << 6;

  floatx4 acc[4][4];
#pragma unroll
  for (int a = 0; a < 4; ++a)
#pragma unroll
    for (int b = 0; b < 4; ++b) acc[a][b] = (floatx4)0.f;

  for (int s = 0; s < 8; ++s) {
    const int c0 = (kq << 8) + (s << 5);
    __syncthreads();
    for (int i = w; i < 17; i += 4) {
      int chunk = (i << 6) + lane;
      int p = chunk >> 2, q = chunk & 3;
      int r = p / 68, xs = p - r * 68;
      int y = y0 - 1 + r, xg = xs - 1;
      bool ok = ((unsigned)y < 64u) && ((unsigned)xg < 64u);
      size_t off = (((size_t)(n << 12) + (y << 6) + xg) << 9) + c0 + (q << 3);
      const void* gh = ok ? (const void*)(xhi + off) : (const void*)guard;
      const void* gl = ok ? (const void*)(xlo + off) : (const void*)guard;
      gl_lds16(gh, (char*)aHi + (i << 10));
      gl_lds16(gl, (char*)aLo + (i << 10));
    }
    for (int tt = 0; tt < 9; ++tt) {
      if (tt > 0) __syncthreads();
      for (int i = w; i < 8; i += 4) {
        int chunk = (i << 6) + lane;
        int row = chunk >> 2, q = chunk & 3;
        size_t off = ((size_t)((tt << 9) + o0 + row) << 9) + c0 + (q << 3);
        gl_lds16((const void*)(whi + off), (char*)bHi + (i << 10));
        gl_lds16((const void*)(wlo + off), (char*)bLo + (i << 10));
      }
      __syncthreads();

      const int dy = tt / 3, dx = tt - 3 * dy;
      half8 ah[4], al[4], bh[4], bl[4];
#pragma unroll
      for (int im = 0; im < 4; ++im) {
        int xp = (im << 4) + l15;
        int p = (ry + dy) * 68 + xp + dx;
        ah[im] = *(const half8*)&aHi[(p << 5) + (l16 << 3)];
        al[im] = *(const half8*)&aLo[(p << 5) + (l16 << 3)];
      }
#pragma unroll
      for (int in = 0; in < 4; ++in) {
        int orow = wo + (in << 4) + l15;
        bh[in] = *(const half8*)&bHi[(orow << 5) + (l16 << 3)];
        bl[in] = *(const half8*)&bLo[(orow << 5) + (l16 << 3)];
      }
#pragma unroll
      for (int im = 0; im < 4; ++im)
#pragma unroll
        for (int in = 0; in < 4; ++in) {
          acc[im][in] = __builtin_amdgcn_mfma_f32_16x16x32_f16(
              ah[im], bh[in], acc[im][in], 0, 0, 0);
          acc[im][in] = __builtin_amdgcn_mfma_f32_16x16x32_f16(
              ah[im], bl[in], acc[im][in], 0, 0, 0);
          acc[im][in] = __builtin_amdgcn_mfma_f32_16x16x32_f16(
              al[im], bh[in], acc[im][in], 0, 0, 0);
        }
    }
  }

#pragma unroll
  for (int im = 0; im < 4; ++im)
#pragma unroll
    for (int in = 0; in < 4; ++in) {
      int o = o0 + wo + (in << 4) + l15;
#pragma unroll
      for (int reg = 0; reg < 4; ++reg) {
        int m_local = (ry << 6) + (im << 4) + (l16 << 2) + reg;
        size_t off = (((size_t)(n << 12) + (y0 << 6) + m_local) << 9) + o;
        atomicAdd(&hout[off], acc[im][in][reg]);
      }
    }
}

// ---------------------------------------------------------------------------
// 2. 1x1 heads + softmax. grid (64 y, 2 n), block 256.
// ---------------------------------------------------------------------------
__global__ __launch_bounds__(256) void head_kernel(
    const float* __restrict__ hbuf, const float* __restrict__ cb,
    const float* __restrict__ wslt, const float* __restrict__ wslb,
    float* __restrict__ out, float* __restrict__ fgbuf) {
  const int y = blockIdx.x, n = blockIdx.y;
  __shared__ float sH[16 * 65];
  __shared__ float sWt[1024];
  __shared__ float sOut[64 * 65];
  const int tid = threadIdx.x;
  const int x = tid & 63, og = tid >> 6;

  float acc[16];
#pragma unroll
  for (int j = 0; j < 16; ++j) acc[j] = 0.f;

  const float* hb = hbuf + (((size_t)(n << 12) + (y << 6)) << 9);

  for (int c0 = 0; c0 < 512; c0 += 16) {
    __syncthreads();
#pragma unroll
    for (int p = 0; p < 4; ++p) {
      int e = tid + (p << 8);
      {
        int cc = e & 15, xx = e >> 4;
        float raw = hb[((size_t)xx << 9) + c0 + cc];
        sH[cc * 65 + xx] = fmaxf(raw * HSCALE + cb[c0 + cc], 0.f);
      }
      {
        int cc = e >> 6, xx = e & 63;
        sWt[e] = wslt[((c0 + cc) << 6) + xx];
      }
    }
    __syncthreads();
#pragma unroll
    for (int cc = 0; cc < 16; ++cc) {
      float hv = sH[cc * 65 + x];
      const float4* wp = (const float4*)&sWt[(cc << 6) + (og << 4)];
      float4 w0 = wp[0], w1 = wp[1], w2 = wp[2], w3 = wp[3];
      acc[0]  = fmaf(hv, w0.x, acc[0]);  acc[1]  = fmaf(hv, w0.y, acc[1]);
      acc[2]  = fmaf(hv, w0.z, acc[2]);  acc[3]  = fmaf(hv, w0.w, acc[3]);
      acc[4]  = fmaf(hv, w1.x, acc[4]);  acc[5]  = fmaf(hv, w1.y, acc[5]);
      acc[6]  = fmaf(hv, w1.z, acc[6]);  acc[7]  = fmaf(hv, w1.w, acc[7]);
      acc[8]  = fmaf(hv, w2.x, acc[8]);  acc[9]  = fmaf(hv, w2.y, acc[9]);
      acc[10] = fmaf(hv, w2.z, acc[10]); acc[11] = fmaf(hv, w2.w, acc[11]);
      acc[12] = fmaf(hv, w3.x, acc[12]); acc[13] = fmaf(hv, w3.y, acc[13]);
      acc[14] = fmaf(hv, w3.z, acc[14]); acc[15] = fmaf(hv, w3.w, acc[15]);
    }
  }
  __syncthreads();
#pragma unroll
  for (int j = 0; j < 16; ++j) {
    int o = (og << 4) + j;
    sOut[o * 65 + x] = acc[j] + wslb[o];
  }
  __syncthreads();

  const int p0 = (n << 12) + (y << 6);
  float* locs = out + O0 + (size_t)p0 * 36;
  for (int e = tid; e < 2304; e += 256) {
    int xx = e / 36, o = e - xx * 36;
    locs[e] = sOut[o * 65 + xx];
  }
  float* scrs = out + O1 + (size_t)p0 * 18;
  for (int e = tid; e < 1152; e += 256) {
    int xx = e / 18, ss = e - xx * 18;
    scrs[e] = sOut[(36 + ss) * 65 + xx];
  }
  float* fg = fgbuf + n * NANCH + (y << 6) * 9;
  for (int e = tid; e < 576; e += 256) {
    int xx = e / 9, a = e - xx * 9;
    float s0 = sOut[(36 + 2 * a) * 65 + xx];
    float s1 = sOut[(36 + 2 * a + 1) * 65 + xx];
    fg[e] = 1.0f / (1.0f + expf(s0 - s1));
  }
}

// ---------------------------------------------------------------------------
// 3. anchors + decode + clip + min-size + sort keys (+ init out regions).
// ---------------------------------------------------------------------------
__global__ __launch_bounds__(256) void decode_kernel(
    const float* __restrict__ out0, const float* __restrict__ fgbuf,
    float4* __restrict__ roibuf, u64* __restrict__ keys,
    float* __restrict__ anchor_out, float* __restrict__ out,
    const int* __restrict__ imgh_p, const int* __restrict__ imgw_p) {
  int gid = blockIdx.x * 256 + threadIdx.x;   // < 131072
  if (gid < 3600) {
    if (gid < 2400) out[O2 + gid] = 0.f;
    else if (gid < 3000) out[O3 + (gid - 2400)] = (float)((gid - 2400) / 300);
    else out[O5 + (gid - 3000)] = 0.f;
  }
  int n = gid >> 16, k = gid & (SEG - 1);
  if (k >= NANCH) { keys[gid] = ~0ull; return; }
  int a = k % 9;
  int p = k / 9;
  int py = p >> 6, px = p & 63;

  const double R[3] = {0.5, 1.0, 2.0};
  const double S[3] = {8.0, 16.0, 32.0};
  double r = R[a / 3], s = S[a - (a / 3) * 3];
  double hd = 16.0 * s * sqrt(r);
  double wd = 16.0 * s * sqrt(1.0 / r);
  float ay1 = (float)(8.0 - hd / 2.0) + (float)(py * 16);
  float ax1 = (float)(8.0 - wd / 2.0) + (float)(px * 16);
  float ay2 = (float)(8.0 + hd / 2.0) + (float)(py * 16);
  float ax2 = (float)(8.0 + wd / 2.0) + (float)(px * 16);
  if (n == 0) {
    float* ao = anchor_out + (size_t)k * 4;
    ao[0] = ay1; ao[1] = ax1; ao[2] = ay2; ao[3] = ax2;
  }
  float ahk = ay2 - ay1, awk = ax2 - ax1;
  float acy = ay1 + 0.5f * ahk, acx = ax1 + 0.5f * awk;
  const float* lp = out0 + ((size_t)(n * NANCH + k) << 2);
  float dy = lp[0], dx = lp[1], dh = lp[2], dw = lp[3];
  float cy = dy * ahk + acy;
  float cx = dx * awk + acx;
  float bh = expf(dh) * ahk;
  float bw = expf(dw) * awk;
  float img_h = (float)imgh_p[0], img_w = (float)imgw_p[0];
  float y1 = fminf(fmaxf(cy - 0.5f * bh, 0.f), img_h);
  float x1 = fminf(fmaxf(cx - 0.5f * bw, 0.f), img_w);
  float y2 = fminf(fmaxf(cy + 0.5f * bh, 0.f), img_h);
  float x2 = fminf(fmaxf(cx + 0.5f * bw, 0.f), img_w);
  bool valid = ((y2 - y1) >= 16.f) && ((x2 - x1) >= 16.f);
  float sc = valid ? fgbuf[n * NANCH + k] : -INFINITY;
  roibuf[n * NANCH + k] = make_float4(y1, x1, y2, x2);
  unsigned int b = __float_as_uint(sc);
  unsigned int m = b ^ ((b & 0x80000000u) ? 0xFFFFFFFFu : 0x80000000u);
  keys[gid] = ((u64)(~m) << 32) | (unsigned int)k;
}

// ---------------------------------------------------------------------------
// 5. bitonic sort (u64 keys, ascending per 65536 segment), 11 launches
// ---------------------------------------------------------------------------
__global__ __launch_bounds__(256) void sort_local_a(u64* __restrict__ keys) {
  __shared__ u64 sk[4096];
  const int base = blockIdx.x << 12;
  for (int e = threadIdx.x; e < 4096; e += 256) sk[e] = keys[base + e];
  __syncthreads();
  for (int k = 2; k <= 4096; k <<= 1) {
    for (int j = k >> 1; j > 0; j >>= 1) {
      for (int t = threadIdx.x; t < 2048; t += 256) {
        int l = ((t & ~(j - 1)) << 1) | (t & (j - 1));
        int rr = l | j;
        bool asc = (((base + l) & k) == 0);
        u64 a = sk[l], b = sk[rr];
        if ((a > b) == asc) { sk[l] = b; sk[rr] = a; }
      }
      __syncthreads();
    }
  }
  for (int e = threadIdx.x; e < 4096; e += 256) keys[base + e] = sk[e];
}

__global__ __launch_bounds__(256) void sort_global_pass(u64* __restrict__ keys,
                                                        int k, int j) {
  int t = blockIdx.x * 256 + threadIdx.x;
  int l = ((t & ~(j - 1)) << 1) | (t & (j - 1));
  int rr = l | j;
  bool asc = (((l & (SEG - 1)) & k) == 0);
  u64 a = keys[l], b = keys[rr];
  if ((a > b) == asc) { keys[l] = b; keys[rr] = a; }
}

__global__ __launch_bounds__(256) void sort_global_pass2(u64* __restrict__ keys,
                                                         int k, int j1) {
  int t = blockIdx.x * 256 + threadIdx.x;
  int j2 = j1 >> 1;
  int l = ((t & ~(j2 - 1)) << 1) | (t & (j2 - 1));
  l = ((l & ~(j1 - 1)) << 1) | (l & (j1 - 1));
  u64 e0 = keys[l], e1 = keys[l | j2], e2 = keys[l | j1], e3 = keys[l | j1 | j2];
  bool asc = (((l & (SEG - 1)) & k) == 0);
  u64 tmp;
  if ((e0 > e2) == asc) { tmp = e0; e0 = e2; e2 = tmp; }
  if ((e1 > e3) == asc) { tmp = e1; e1 = e3; e3 = tmp; }
  if ((e0 > e1) == asc) { tmp = e0; e0 = e1; e1 = tmp; }
  if ((e2 > e3) == asc) { tmp = e2; e2 = e3; e3 = tmp; }
  keys[l] = e0; keys[l | j2] = e1; keys[l | j1] = e2; keys[l | j1 | j2] = e3;
}

__global__ __launch_bounds__(256) void sort_local_b(u64* __restrict__ keys, int k) {
  __shared__ u64 sk[4096];
  const int base = blockIdx.x << 12;
  for (int e = threadIdx.x; e < 4096; e += 256) sk[e] = keys[base + e];
  __syncthreads();
  for (int j = 2048; j > 0; j >>= 1) {
    for (int t = threadIdx.x; t < 2048; t += 256) {
      int l = ((t & ~(j - 1)) << 1) | (t & (j - 1));
      int rr = l | j;
      bool asc = ((((base + l) & (SEG - 1)) & k) == 0);
      u64 a = sk[l], b = sk[rr];
      if ((a > b) == asc) { sk[l] = b; sk[rr] = a; }
    }
    __syncthreads();
  }
  for (int e = threadIdx.x; e < 4096; e += 256) keys[base + e] = sk[e];
}

// ---------------------------------------------------------------------------
// 6a. gather sorted boxes + alive bitmask words. grid (24, 2), block 256.
// ---------------------------------------------------------------------------
__global__ __launch_bounds__(256) void nms_gather(
    const u64* __restrict__ keys, const float4* __restrict__ roibuf,
    float4* __restrict__ sbox, u64* __restrict__ alive) {
  const int n = blockIdx.y;
  int i = blockIdx.x * 256 + threadIdx.x;  // 0..6143
  u64 kk = (i < N_PRE) ? keys[(n << 16) + i] : ~0ull;
  bool valid = ((unsigned)(kk >> 32)) < 0xFF800000u;
  float4 b = make_float4(0.f, 0.f, 0.f, 0.f);
  if (valid) b = roibuf[(size_t)n * NANCH + (unsigned)(kk & 0xFFFFFFFFull)];
  sbox[n * NPADC + i] = b;
  u64 bal = __ballot(valid);
  if ((threadIdx.x & 63) == 0) alive[n * NW + (i >> 6)] = bal;
}

// ---------------------------------------------------------------------------
// 6b. build FULL suppression matrix (both triangles; symmetric).
// M[n][i][w] bit b = IoU(box i, box 64w+b) > 0.7.
// grid (96 row-groups, 4 w-quarters, 2 n), block 256 (4 waves, wave wv does
// w = q*24 + it*4 + wv). Per-wave LDS staging, no barriers needed.
// ---------------------------------------------------------------------------
__global__ __launch_bounds__(256) void build_mask(
    const float4* __restrict__ sbox, u64* __restrict__ M) {
  __shared__ float4 jb[4][64];
  __shared__ float ja[4][64];
  const int tid = threadIdx.x, lane = tid & 63, wv = tid >> 6;
  const int g = blockIdx.x, q = blockIdx.y, n = blockIdx.z;
  const float4* sb = sbox + n * NPADC;
  float4 bi = sb[(g << 6) + lane];
  float ai = (bi.z - bi.x) * (bi.w - bi.y);
  u64* Mrow = M + ((size_t)(n * NPADC + (g << 6) + lane)) * NW;
#pragma unroll
  for (int it = 0; it < 6; ++it) {
    int w = q * 24 + (it << 2) + wv;
    float4 bjl = sb[(w << 6) + lane];
    jb[wv][lane] = bjl;
    ja[wv][lane] = (bjl.z - bjl.x) * (bjl.w - bjl.y);
    // wave-coherent LDS: no cross-wave sharing, no barrier needed
    u64 bits = 0;
#pragma unroll 8
    for (int j = 0; j < 64; ++j) {
      float4 bj = jb[wv][j];
      float aj = ja[wv][j];
      float ih = fmaxf(fminf(bi.z, bj.z) - fmaxf(bi.x, bj.x), 0.f);
      float iw = fmaxf(fminf(bi.w, bj.w) - fmaxf(bi.y, bj.y), 0.f);
      float inter = ih * iw;
      bool bit = inter / (ai + aj - inter + 1e-9f) > 0.7f;
      bits |= ((u64)bit) << j;
    }
    Mrow[w] = bits;
  }
}

// ---------------------------------------------------------------------------
// 6c. serial greedy reduce, one wave per image. R4: 161 us — every kept-row
// OR and every sbox read was its own dependent ~900-cyc global round-trip.
// Now: rolling prefetch of diag word + sbox (next chunk), 8-wide batched OR
// loads (one vmcnt wait per chunk). Full matrix -> unconditional ORs.
// ---------------------------------------------------------------------------
__global__ __launch_bounds__(64) void nms_reduce(
    const u64* __restrict__ M, const u64* __restrict__ alive,
    const float4* __restrict__ sbox, float* __restrict__ out) {
  const int n = blockIdx.x, lane = threadIdx.x;
  float* rois = out + O2 + n * (N_POST * 4);
  float* vmask = out + O5 + n * N_POST;
  const u64* A = alive + n * NW;
  const u64* Mb = M + (size_t)n * NPADC * NW;
  const float4* sb = sbox + n * NPADC;
  u64 aw0 = A[lane];
  u64 aw1 = (lane < 32) ? A[64 + lane] : 0ull;
  u64 accA = 0, accB = 0;   // lane L: suppressed words L and 64+L (L<32)
  int nk = 0;
  u64 dnext = Mb[(size_t)lane * NW + 0];
  float4 bnext = sb[lane];
  const u64 below = lane ? (~0ull >> (64 - lane)) : 0ull;

  for (int c = 0; c < 94; ++c) {
    u64 dcur = dnext;
    float4 bcur = bnext;
    if (c + 1 < 94) {
      dnext = Mb[(size_t)(((c + 1) << 6) + lane) * NW + (c + 1)];
      bnext = sb[((c + 1) << 6) + lane];
    }
    u64 wacc = (c < 64) ? bcast64(accA, c) : bcast64(accB, c - 64);
    u64 aw = (c < 64) ? bcast64(aw0, c) : bcast64(aw1, c - 64);
    u64 alive_u = aw & ~wacc;
    if (alive_u == 0ull) continue;

    u64 dmask = dcur & below;  // suppressors j < lane within chunk
    u64 rem = alive_u, kept = 0;
    while (rem) {
      int j = __builtin_ctzll(rem);          // uniform across wave
      kept |= 1ull << j;
      u64 col = __ballot((dmask >> j) & 1);  // who j suppresses (i > j)
      rem &= ~(col | (1ull << j));
    }

    int npop = __popcll(kept);
    if ((kept >> lane) & 1ull) {
      int slot = nk + __popcll(kept & below);
      if (slot < N_POST) {
        rois[slot * 4 + 0] = bcur.x; rois[slot * 4 + 1] = bcur.y;
        rois[slot * 4 + 2] = bcur.z; rois[slot * 4 + 3] = bcur.w;
        vmask[slot] = 1.0f;
      }
    }
    if (nk + npop >= N_POST) break;
    nk += npop;

    // 8-wide batched OR of kept rows: 8 independent loads -> one wait
    u64 kk = kept;
    while (kk) {
      int j0 = __builtin_ctzll(kk); kk &= kk - 1;
      int j1 = kk ? __builtin_ctzll(kk) : j0; kk &= kk - 1;
      int j2 = kk ? __builtin_ctzll(kk) : j0; kk &= kk - 1;
      int j3 = kk ? __builtin_ctzll(kk) : j0; kk &= kk - 1;
      int j4 = kk ? __builtin_ctzll(kk) : j0; kk &= kk - 1;
      int j5 = kk ? __builtin_ctzll(kk) : j0; kk &= kk - 1;
      int j6 = kk ? __builtin_ctzll(kk) : j0; kk &= kk - 1;
      int j7 = kk ? __builtin_ctzll(kk) : j0; kk &= kk - 1;
      const u64* r0 = Mb + (size_t)((c << 6) + j0) * NW;
      const u64* r1 = Mb + (size_t)((c << 6) + j1) * NW;
      const u64* r2 = Mb + (size_t)((c << 6) + j2) * NW;
      const u64* r3 = Mb + (size_t)((c << 6) + j3) * NW;
      const u64* r4 = Mb + (size_t)((c << 6) + j4) * NW;
      const u64* r5 = Mb + (size_t)((c << 6) + j5) * NW;
      const u64* r6 = Mb + (size_t)((c << 6) + j6) * NW;
      const u64* r7 = Mb + (size_t)((c << 6) + j7) * NW;
      u64 oA = r0[lane] | r1[lane] | r2[lane] | r3[lane]
             | r4[lane] | r5[lane] | r6[lane] | r7[lane];
      u64 oB = 0;
      if (lane < 32)
        oB = r0[64 + lane] | r1[64 + lane] | r2[64 + lane] | r3[64 + lane]
           | r4[64 + lane] | r5[64 + lane] | r6[64 + lane] | r7[64 + lane];
      accA |= oA;
      accB |= oB;
    }
  }
}

// ---------------------------------------------------------------------------
extern "C" void kernel_launch(void* const* d_in, const int* in_sizes, int n_in,
                              void* d_out, int out_size, void* d_ws, size_t ws_size,
                              hipStream_t stream) {
  const float* x        = (const float*)d_in[0];
  const float* conv1_w  = (const float*)d_in[1];
  const float* conv1_b  = (const float*)d_in[2];
  const float* score_w  = (const float*)d_in[3];
  const float* score_b  = (const float*)d_in[4];
  const float* loc_w    = (const float*)d_in[5];
  const float* loc_b    = (const float*)d_in[6];
  const int*   imgh_p   = (const int*)d_in[7];
  const int*   imgw_p   = (const int*)d_in[8];

  float* out = (float*)d_out;
  float* ws  = (float*)d_ws;

  _Float16* xhi = (_Float16*)(ws + WS_XHI);
  _Float16* xlo = (_Float16*)(ws + WS_XLO);
  _Float16* whi = (_Float16*)(ws + WS_WHI);
  _Float16* wlo = (_Float16*)(ws + WS_WLO);
  float* wslt   = ws + WS_WSLT;
  float* wslb   = ws + WS_WSLB;
  float* hbuf   = ws + WS_H;
  float* guard  = ws + WS_GUARD;
  // overlays (xhi region is dead after conv)
  float* fgbuf   = ws + WS_FG;
  float4* roibuf = (float4*)(ws + WS_ROI);
  u64* keys      = (u64*)(ws + WS_KEYS);
  float4* sbox   = (float4*)(ws + WS_SBOX);
  u64* alive     = (u64*)(ws + WS_ALIVE);
  u64* maskbuf   = (u64*)(ws + WS_MASK);   // overlays whi/wlo (dead after conv)

  prep_all<<<5826, 256, 0, stream>>>(x, conv1_w, loc_w, score_w, loc_b, score_b,
                                     (float4*)hbuf, (float4*)guard,
                                     xhi, xlo, whi, wlo, wslt, wslb);

  conv_mfma<<<dim3(64, 4, 2), 256, 0, stream>>>(xhi, xlo, whi, wlo, guard, hbuf);

  head_kernel<<<dim3(64, 2), 256, 0, stream>>>(hbuf, conv1_b, wslt, wslb, out, fgbuf);
  decode_kernel<<<512, 256, 0, stream>>>(out, fgbuf, roibuf, keys,
                                         out + O4, out, imgh_p, imgw_p);

  sort_local_a<<<32, 256, 0, stream>>>(keys);
  for (int k = 8192; k <= SEG; k <<= 1) {
    int j = k >> 1;
    while (j >= 4096) {
      if (j >= 8192) {
        sort_global_pass2<<<128, 256, 0, stream>>>(keys, k, j);
        j >>= 2;
      } else {
        sort_global_pass<<<256, 256, 0, stream>>>(keys, k, j);
        j >>= 1;
      }
    }
    sort_local_b<<<32, 256, 0, stream>>>(keys, k);
  }

  nms_gather<<<dim3(24, 2), 256, 0, stream>>>(keys, roibuf, sbox, alive);
  build_mask<<<dim3(96, 4, 2), 256, 0, stream>>>(sbox, maskbuf);
  nms_reduce<<<2, 64, 0, stream>>>(maskbuf, alive, sbox, out);
}